// Round 1
// 258.218 us; speedup vs baseline: 1.0060x; 1.0060x over previous
//
#include <hip/hip_runtime.h>
#include <math.h>

// Problem constants
#define NB   64
#define TT   2048
// Tail-window truncation: output = x[:, 2047]; the only temporal coupling is
// the LIF membrane (decay 0.5/step + hard reset). v(T0)=0 direct error at
// 2047 is 0.5^63; validated in prior rounds (TW=192 matched full scan).
#define TW   64
#define T0   (TT - TW)     // 1984
#define NR   (NB * TW)     // 4096 active rows

__device__ __forceinline__ float gelu_exact(float x) {
    return 0.5f * x * (1.0f + erff(x * 0.7071067811865476f));
}

// ---------------- Projector stage 1: G = gelu(hist @ pw1 + pb1)  [NR,64] ----
__global__ void proj1_kernel(const float* __restrict__ hist, const float* __restrict__ pw1,
                             const float* __restrict__ pb1, float* __restrict__ G) {
    int tid = blockIdx.x * 256 + threadIdx.x;     // NR*64 threads
    int r = tid >> 6, j = tid & 63;
    int b = r >> 6, t = r & (TW - 1);              // window-local row -> (b, T0+t)
    const float* h = hist + ((size_t)b * TT + (T0 + t)) * 4;
    float acc = pb1[j];
    acc += h[0] * pw1[0*64 + j];
    acc += h[1] * pw1[1*64 + j];
    acc += h[2] * pw1[2*64 + j];
    acc += h[3] * pw1[3*64 + j];
    G[(size_t)r * 64 + j] = gelu_exact(acc);
}

// ---------------- Projector stage 2: X = G @ pw2 + pb2  [NR,128] ------------
__global__ void __launch_bounds__(512) proj2_kernel(const float* __restrict__ G,
        const float* __restrict__ pw2, const float* __restrict__ pb2,
        float* __restrict__ X) {
    __shared__ float Wc[64*128];     // 32KB
    int wave = threadIdx.x >> 6, lane = threadIdx.x & 63;
    for (int i = threadIdx.x; i < 64*128/4; i += 512)
        ((float4*)Wc)[i] = ((const float4*)pw2)[i];
    __syncthreads();
    float2 bv = ((const float2*)pb2)[lane];
    int tile = blockIdx.x * 8 + wave;             // exact fit: 512 tiles
    int rb = __builtin_amdgcn_readfirstlane(tile) * 8;
    const float* __restrict__ x0 = G + (size_t)rb * 64;
    float2 acc[8];
    #pragma unroll
    for (int r = 0; r < 8; ++r) acc[r] = make_float2(0.f, 0.f);
    #pragma unroll 2
    for (int k4 = 0; k4 < 16; ++k4) {
        float4 xr[8];
        #pragma unroll
        for (int r = 0; r < 8; ++r)
            xr[r] = *(const float4*)(x0 + r*64 + k4*4);   // s_load_dwordx4
        #pragma unroll
        for (int kk = 0; kk < 4; ++kk) {
            float2 w = ((const float2*)(Wc + (k4*4 + kk)*128))[lane];
            #pragma unroll
            for (int r = 0; r < 8; ++r) {
                float xv = ((const float*)&xr[r])[kk];    // SGPR operand
                acc[r].x += xv * w.x;
                acc[r].y += xv * w.y;
            }
        }
    }
    #pragma unroll
    for (int r = 0; r < 8; ++r) {
        float2 o; o.x = acc[r].x + bv.x; o.y = acc[r].y + bv.y;
        ((float2*)(X + (size_t)(rb + r) * 128))[lane] = o;
    }
}

// ---------------- fc1 + LN + LIF1 (fused, batch-aligned blocks) -------------
// Block b owns batch b's 64 rows. GEMM: 8 waves x 8 rows, W staged in 64KB
// K-halves. After the K-loop the Wc buffer is dead -> reuse it as the H tile
// [64][256] (H never touches HBM). LIF1 chains run in-LDS; spikes -> global.
__global__ void __launch_bounds__(512) fc1_kernel(const float* __restrict__ Xin,
        const float* __restrict__ W, const float* __restrict__ bias,
        const float* __restrict__ gamma, const float* __restrict__ beta,
        float* __restrict__ Spk) {
    __shared__ float Wc[64*256];     // 64KB: K-half staging, then H[64][256]
    int wave = threadIdx.x >> 6, lane = threadIdx.x & 63;
    float4 bv  = ((const float4*)bias)[lane];
    float4 gv  = ((const float4*)gamma)[lane];
    float4 btv = ((const float4*)beta)[lane];
    int b = blockIdx.x;
    int rb = __builtin_amdgcn_readfirstlane(b * 64 + (threadIdx.x >> 6) * 8);
    const float* __restrict__ x0 = Xin + (size_t)rb * 128;
    float4 acc[8];
    #pragma unroll
    for (int r = 0; r < 8; ++r) acc[r] = make_float4(0.f,0.f,0.f,0.f);
    for (int h = 0; h < 2; ++h) {
        __syncthreads();
        const float4* Wh = (const float4*)(W + h*64*256);
        for (int i = threadIdx.x; i < 64*256/4; i += 512)
            ((float4*)Wc)[i] = Wh[i];
        __syncthreads();
        const float* __restrict__ xh = x0 + h*64;
        #pragma unroll 2
        for (int k4 = 0; k4 < 16; ++k4) {
            float4 xr[8];
            #pragma unroll
            for (int r = 0; r < 8; ++r)
                xr[r] = *(const float4*)(xh + r*128 + k4*4);   // s_load_dwordx4
            #pragma unroll
            for (int kk = 0; kk < 4; ++kk) {
                float4 w = ((const float4*)(Wc + (k4*4 + kk)*256))[lane];
                #pragma unroll
                for (int r = 0; r < 8; ++r) {
                    float xv = ((const float*)&xr[r])[kk];     // SGPR operand
                    acc[r].x += xv * w.x; acc[r].y += xv * w.y;
                    acc[r].z += xv * w.z; acc[r].w += xv * w.w;
                }
            }
        }
    }
    // LayerNorm per row, in registers
    #pragma unroll
    for (int r = 0; r < 8; ++r) {
        float4 a = acc[r];
        a.x += bv.x; a.y += bv.y; a.z += bv.z; a.w += bv.w;
        float s = a.x + a.y + a.z + a.w;
        #pragma unroll
        for (int m = 1; m < 64; m <<= 1) s += __shfl_xor(s, m, 64);
        float mean = s * (1.0f/256.0f);
        float dx = a.x - mean, dy = a.y - mean, dz = a.z - mean, dw = a.w - mean;
        float q2 = dx*dx + dy*dy + dz*dz + dw*dw;
        #pragma unroll
        for (int m = 1; m < 64; m <<= 1) q2 += __shfl_xor(q2, m, 64);
        float inv = 1.0f / sqrtf(q2 * (1.0f/256.0f) + 1e-5f);
        acc[r].x = dx*inv*gv.x + btv.x; acc[r].y = dy*inv*gv.y + btv.y;
        acc[r].z = dz*inv*gv.z + btv.z; acc[r].w = dw*inv*gv.w + btv.w;
    }
    __syncthreads();                 // all waves done reading Wc (K-loop)
    #pragma unroll
    for (int r = 0; r < 8; ++r)
        ((float4*)(Wc + (wave*8 + r)*256))[lane] = acc[r];   // H tile -> LDS
    __syncthreads();
    // LIF1: thread d chains its column over the 64-step window (in LDS)
    if (threadIdx.x < 256) {
        int d = threadIdx.x;
        float* __restrict__ sp = Spk + (size_t)b * 64 * 256 + d;
        float v = 0.f;
        #pragma unroll 8
        for (int t = 0; t < 64; ++t) {
            float x = Wc[t*256 + d];
            v += (x - v) * 0.5f;
            bool s = (v >= 1.f);
            sp[t*256] = s ? 1.f : 0.f;
            v = s ? 0.f : v;
        }
    }
}

// ---------------- fc2 + LN + LIF2 + residual (fused) ------------------------
// Block b owns batch b. Y tile lives only in LDS (reused Wc). LIF2 + residual
// update X in place; final layer writes out row t=63.
__global__ void __launch_bounds__(512) fc2_kernel(const float* __restrict__ SF,
        const float* __restrict__ W, const float* __restrict__ bias,
        const float* __restrict__ gamma, const float* __restrict__ beta,
        float* __restrict__ X, float* __restrict__ out, int writeOut) {
    __shared__ float Wc[128*128];    // 64KB: K-half staging, then Y[64][128]
    int wave = threadIdx.x >> 6, lane = threadIdx.x & 63;
    float2 bv  = ((const float2*)bias)[lane];
    float2 gv  = ((const float2*)gamma)[lane];
    float2 btv = ((const float2*)beta)[lane];
    int b = blockIdx.x;
    int rb = __builtin_amdgcn_readfirstlane(b * 64 + (threadIdx.x >> 6) * 8);
    const float* __restrict__ x0 = SF + (size_t)rb * 256;
    float2 acc[8];
    #pragma unroll
    for (int r = 0; r < 8; ++r) acc[r] = make_float2(0.f, 0.f);
    for (int h = 0; h < 2; ++h) {
        __syncthreads();
        const float4* Wh = (const float4*)(W + h*128*128);
        for (int i = threadIdx.x; i < 128*128/4; i += 512)
            ((float4*)Wc)[i] = Wh[i];
        __syncthreads();
        const float* __restrict__ xh = x0 + h*128;
        #pragma unroll 2
        for (int k4 = 0; k4 < 32; ++k4) {
            float4 xr[8];
            #pragma unroll
            for (int r = 0; r < 8; ++r)
                xr[r] = *(const float4*)(xh + r*256 + k4*4);   // s_load_dwordx4
            #pragma unroll
            for (int kk = 0; kk < 4; ++kk) {
                float2 w = ((const float2*)(Wc + (k4*4 + kk)*128))[lane];
                #pragma unroll
                for (int r = 0; r < 8; ++r) {
                    float xv = ((const float*)&xr[r])[kk];
                    acc[r].x += xv * w.x;
                    acc[r].y += xv * w.y;
                }
            }
        }
    }
    // LayerNorm per row, in registers
    #pragma unroll
    for (int r = 0; r < 8; ++r) {
        float2 a = acc[r];
        a.x += bv.x; a.y += bv.y;
        float s = a.x + a.y;
        #pragma unroll
        for (int m = 1; m < 64; m <<= 1) s += __shfl_xor(s, m, 64);
        float mean = s * (1.0f/128.0f);
        float dx = a.x - mean, dy = a.y - mean;
        float q = dx*dx + dy*dy;
        #pragma unroll
        for (int m = 1; m < 64; m <<= 1) q += __shfl_xor(q, m, 64);
        float inv = 1.0f / sqrtf(q * (1.0f/128.0f) + 1e-5f);
        acc[r].x = dx*inv*gv.x + btv.x;
        acc[r].y = dy*inv*gv.y + btv.y;
    }
    __syncthreads();                 // all waves done reading Wc (K-loop)
    #pragma unroll
    for (int r = 0; r < 8; ++r)
        ((float2*)(Wc + (wave*8 + r)*128))[lane] = acc[r];   // Y tile -> LDS
    __syncthreads();
    // LIF2 + residual: thread n chains its column; X updated in place
    if (threadIdx.x < 128) {
        int n = threadIdx.x;
        float* __restrict__ xp = X + (size_t)b * 64 * 128 + n;
        float v = 0.f, xl = 0.f;
        #pragma unroll 8
        for (int t = 0; t < 64; ++t) {
            float y = Wc[t*128 + n];
            v += (y - v) * 0.5f;
            bool s = (v >= 1.f);
            float xn = xp[t*128] + (s ? 1.f : 0.f);
            xp[t*128] = xn;
            xl = xn;
            v = s ? 0.f : v;
        }
        if (writeOut) out[b * 128 + n] = xl;   // row t=2047 per (b,n)
    }
}

extern "C" void kernel_launch(void* const* d_in, const int* in_sizes, int n_in,
                              void* d_out, int out_size, void* d_ws, size_t ws_size,
                              hipStream_t stream) {
    const float* hist = (const float*)d_in[0];
    const float* pw1  = (const float*)d_in[1];
    const float* pb1  = (const float*)d_in[2];
    const float* pw2  = (const float*)d_in[3];
    const float* pb2  = (const float*)d_in[4];
    const float* fc1w = (const float*)d_in[5];
    const float* fc1b = (const float*)d_in[6];
    const float* n1g  = (const float*)d_in[7];
    const float* n1b  = (const float*)d_in[8];
    const float* fc2w = (const float*)d_in[9];
    const float* fc2b = (const float*)d_in[10];
    const float* n2g  = (const float*)d_in[11];
    const float* n2b  = (const float*)d_in[12];
    float* out = (float*)d_out;

    char* ws = (char*)d_ws;
    float* X   = (float*)ws;                    // [NR,128] f32: 2 MiB
    float* Spk = (float*)(ws + (4ull<<20));     // [NR,256] f32: 4 MiB (also G)
    float* G   = Spk;                           // G dead after proj2

    proj1_kernel<<<NR*64/256, 256, 0, stream>>>(hist, pw1, pb1, G);
    proj2_kernel<<<64, 512, 0, stream>>>(G, pw2, pb2, X);
    for (int l = 0; l < 4; ++l) {
        fc1_kernel<<<64, 512, 0, stream>>>(X, fc1w + (size_t)l*128*256,
                                           fc1b + l*256, n1g + l*256, n1b + l*256, Spk);
        fc2_kernel<<<64, 512, 0, stream>>>(Spk, fc2w + (size_t)l*256*128,
                                           fc2b + l*128, n2g + l*128, n2b + l*128,
                                           X, out, (l == 3) ? 1 : 0);
    }
}